// Round 1
// baseline (340.287 us; speedup 1.0000x reference)
//
#include <hip/hip_runtime.h>
#include <hip/hip_bf16.h>

// ScaledDotAttention: B=4, H=16, S=2048, D=64, fp32 in/out, int mask (nonzero = masked out).
// Flash-attention forward, bf16 MFMA (16x16x32), fp32 accumulate, online softmax.

#define SEQ   2048
#define DK    64
#define NBH   64     // B*H
#define KVB   64     // KV tile
#define QB    64     // Q rows per block (16 per wave)
#define LDSTR 72     // padded LDS stride (bf16 elems): 144 B = 36 banks -> conflict-light

typedef float f32x4 __attribute__((ext_vector_type(4)));
typedef short s16x8 __attribute__((ext_vector_type(8)));
typedef short s16x4 __attribute__((ext_vector_type(4)));

__device__ __forceinline__ short f2bf(float f) {
  union { float f; unsigned u; } v; v.f = f;
  return (short)((v.u + 0x7fffu + ((v.u >> 16) & 1u)) >> 16);  // RNE
}

__global__ __launch_bounds__(256) void sda_attn_kernel(
    const float* __restrict__ Q, const float* __restrict__ K,
    const float* __restrict__ V, const int* __restrict__ M,
    float* __restrict__ O) {
  __shared__ __align__(16) short Kl[KVB][LDSTR];
  __shared__ __align__(16) short Vl[KVB][LDSTR];
  __shared__ __align__(16) short Pl[4][16][LDSTR];

  const int bh   = blockIdx.x;       // b*16 + h
  const int qt   = blockIdx.y;
  const int b    = bh >> 4;
  const int tid  = threadIdx.x;
  const int wid  = tid >> 6;
  const int lane = tid & 63;
  const int lr   = lane & 15;        // C-layout col / A-layout row
  const int lg   = lane >> 4;        // lane group 0..3

  const size_t base  = (size_t)bh * SEQ * DK;
  const int    qrow0 = qt * QB + wid * 16;   // this wave's first q row

  // ---- Q fragments in registers, pre-scaled by 1/sqrt(64) ----
  // A-frag layout (16x16x32): lane holds Q[lr][kk*32 + lg*8 + j]
  s16x8 qf[2];
  {
    const float* qp = Q + base + (size_t)(qrow0 + lr) * DK + lg * 8;
#pragma unroll
    for (int kk = 0; kk < 2; ++kk) {
      float4 a  = *(const float4*)(qp + kk * 32);
      float4 b4 = *(const float4*)(qp + kk * 32 + 4);
      float t8[8] = {a.x, a.y, a.z, a.w, b4.x, b4.y, b4.z, b4.w};
#pragma unroll
      for (int j = 0; j < 8; ++j) qf[kk][j] = f2bf(t8[j] * 0.125f);
    }
  }

  f32x4 oacc[4];
#pragma unroll
  for (int i = 0; i < 4; ++i) oacc[i] = (f32x4){0.f, 0.f, 0.f, 0.f};
  float mreg[4] = {-1e30f, -1e30f, -1e30f, -1e30f};
  float lreg[4] = {0.f, 0.f, 0.f, 0.f};

  const int* Mb = M + (size_t)b * SEQ * SEQ;

  // staging mapping: thread t -> key = t/4, d-range = (t%4)*16 .. +16
  const int skey = tid >> 2;
  const int sd   = (tid & 3) * 16;
  const float* Kg0 = K + base + sd;
  const float* Vg0 = V + base + sd;

  for (int kb = 0; kb < SEQ; kb += KVB) {
    __syncthreads();  // previous iteration's LDS reads done

    // ---- mask prefetch (hides VMEM latency under staging + MFMA) ----
    // C layout: row = lg*4 + r (q), col = nb*16 + lr (k)
    int mk[4][4];
#pragma unroll
    for (int nb = 0; nb < 4; ++nb)
#pragma unroll
      for (int r = 0; r < 4; ++r)
        mk[nb][r] = Mb[(size_t)(qrow0 + lg * 4 + r) * SEQ + (kb + nb * 16 + lr)];

    // ---- stage K,V tile: global fp32 -> bf16 LDS (row-major) ----
    {
      const float* kg = Kg0 + (size_t)(kb + skey) * DK;
      const float* vg = Vg0 + (size_t)(kb + skey) * DK;
#pragma unroll
      for (int i = 0; i < 4; ++i) {
        float4 kv = *(const float4*)(kg + 4 * i);
        float4 vv = *(const float4*)(vg + 4 * i);
        s16x4 ks = { f2bf(kv.x), f2bf(kv.y), f2bf(kv.z), f2bf(kv.w) };
        s16x4 vs = { f2bf(vv.x), f2bf(vv.y), f2bf(vv.z), f2bf(vv.w) };
        *(s16x4*)&Kl[skey][sd + 4 * i] = ks;
        *(s16x4*)&Vl[skey][sd + 4 * i] = vs;
      }
    }
    __syncthreads();

    // ---- scores: S = (Q/8) · K^T  (16 q-rows x 64 keys per wave) ----
    f32x4 sacc[4];
#pragma unroll
    for (int nb = 0; nb < 4; ++nb) {
      sacc[nb] = (f32x4){0.f, 0.f, 0.f, 0.f};
#pragma unroll
      for (int kk = 0; kk < 2; ++kk) {
        s16x8 kf = *(const s16x8*)&Kl[nb * 16 + lr][kk * 32 + lg * 8];
        sacc[nb] = __builtin_amdgcn_mfma_f32_16x16x32_bf16(qf[kk], kf, sacc[nb], 0, 0, 0);
      }
    }

    // ---- mask + row max ----
    float pm[4] = {-1e30f, -1e30f, -1e30f, -1e30f};
#pragma unroll
    for (int nb = 0; nb < 4; ++nb)
#pragma unroll
      for (int r = 0; r < 4; ++r) {
        float s = mk[nb][r] ? -1e9f : sacc[nb][r];
        sacc[nb][r] = s;
        pm[r] = fmaxf(pm[r], s);
      }
#pragma unroll
    for (int r = 0; r < 4; ++r) {
#pragma unroll
      for (int off = 1; off < 16; off <<= 1)
        pm[r] = fmaxf(pm[r], __shfl_xor(pm[r], off));
    }

    // ---- online softmax update ----
    float rs[4];
#pragma unroll
    for (int r = 0; r < 4; ++r) {
      float mn = fmaxf(mreg[r], pm[r]);
      float al = __expf(mreg[r] - mn);   // mreg init -1e30 -> al = 0 first tile, no NaN
      mreg[r] = mn;
      lreg[r] *= al;
#pragma unroll
      for (int db = 0; db < 4; ++db) oacc[db][r] *= al;
      rs[r] = 0.f;
    }

    // ---- P = exp(S - m) -> bf16 LDS (per-wave tile, C-layout write) ----
#pragma unroll
    for (int nb = 0; nb < 4; ++nb)
#pragma unroll
      for (int r = 0; r < 4; ++r) {
        float p = __expf(sacc[nb][r] - mreg[r]);
        rs[r] += p;
        Pl[wid][lg * 4 + r][nb * 16 + lr] = f2bf(p);
      }
#pragma unroll
    for (int r = 0; r < 4; ++r) {
#pragma unroll
      for (int off = 1; off < 16; off <<= 1)
        rs[r] += __shfl_xor(rs[r], off);
      lreg[r] += rs[r];
    }

    // same-wave cross-lane RAW through LDS: drain writes before A-frag reads
    asm volatile("s_waitcnt lgkmcnt(0)" ::: "memory");

    // ---- O += P · V ----
#pragma unroll
    for (int kk = 0; kk < 2; ++kk) {
      s16x8 pf = *(const s16x8*)&Pl[wid][lr][kk * 32 + lg * 8];
#pragma unroll
      for (int db = 0; db < 4; ++db) {
        s16x8 vf;
#pragma unroll
        for (int j = 0; j < 8; ++j)
          vf[j] = Vl[kk * 32 + lg * 8 + j][db * 16 + lr];  // column read (scalar) — optimize later
        oacc[db] = __builtin_amdgcn_mfma_f32_16x16x32_bf16(pf, vf, oacc[db], 0, 0, 0);
      }
    }
  }

  // ---- epilogue: O / l, fp32 store ----
#pragma unroll
  for (int r = 0; r < 4; ++r) {
    float inv = 1.0f / lreg[r];
    float* op = O + base + (size_t)(qrow0 + lg * 4 + r) * DK + lr;
#pragma unroll
    for (int db = 0; db < 4; ++db)
      op[db * 16] = oacc[db][r] * inv;
  }
}

extern "C" void kernel_launch(void* const* d_in, const int* in_sizes, int n_in,
                              void* d_out, int out_size, void* d_ws, size_t ws_size,
                              hipStream_t stream) {
  const float* Q = (const float*)d_in[0];
  const float* K = (const float*)d_in[1];
  const float* V = (const float*)d_in[2];
  const int*   M = (const int*)d_in[3];
  float*       O = (float*)d_out;
  dim3 grid(NBH, SEQ / QB);   // x = b*H+h (heads adjacent -> mask L2 reuse), y = q-tile
  sda_attn_kernel<<<grid, 256, 0, stream>>>(Q, K, V, M, O);
}

// Round 2
// 294.266 us; speedup vs baseline: 1.1564x; 1.1564x over previous
//
#include <hip/hip_runtime.h>
#include <hip/hip_bf16.h>

// ScaledDotAttention: B=4, H=16, S=2048, D=64, fp32 in/out, int mask (nonzero = masked out).
// Flash-attention forward, bf16 MFMA (16x16x32), fp32 accumulate, online softmax.
// R2: V transposed in LDS (vector PV B-frag reads), __float2bfloat16 conversions,
//     bit-packed mask via pre-kernel into d_ws (fallback to int loads).

#define SEQ   2048
#define DK    64
#define NB_   4      // batch
#define NBH   64     // B*H
#define KVB   64     // KV tile
#define QB    64     // Q rows per block (16 per wave)
#define LDSTR 72     // padded LDS stride (bf16 elems): 144 B = 36 dwords -> 2-way max on b128 reads

#define MASK_WORDS (NB_ * SEQ * (SEQ / 32))   // 524288 uints = 2 MB

typedef float f32x4 __attribute__((ext_vector_type(4)));
typedef short s16x8 __attribute__((ext_vector_type(8)));
typedef short s16x4 __attribute__((ext_vector_type(4)));

__device__ __forceinline__ short f2bf(float f) {
  __hip_bfloat16 h = __float2bfloat16(f);   // RNE; compiler emits packed cvt where possible
  return *reinterpret_cast<short*>(&h);
}

__global__ __launch_bounds__(256) void mask_pack_kernel(const int* __restrict__ M,
                                                        unsigned* __restrict__ P) {
  int w = blockIdx.x * 256 + threadIdx.x;     // one u32 (32 mask elems) per thread
  const int4* src = (const int4*)M + (size_t)w * 8;
  unsigned bits = 0;
#pragma unroll
  for (int i = 0; i < 8; ++i) {
    int4 v = src[i];
    bits |= ((unsigned)(v.x != 0) << (4 * i)) | ((unsigned)(v.y != 0) << (4 * i + 1)) |
            ((unsigned)(v.z != 0) << (4 * i + 2)) | ((unsigned)(v.w != 0) << (4 * i + 3));
  }
  P[w] = bits;
}

template <bool PACKED>
__global__ __launch_bounds__(256) void sda_attn_kernel(
    const float* __restrict__ Q, const float* __restrict__ K,
    const float* __restrict__ V, const int* __restrict__ M,
    const unsigned* __restrict__ Mp, float* __restrict__ O) {
  __shared__ __align__(16) short Kl[KVB][LDSTR];
  __shared__ __align__(16) short Vt[DK][LDSTR];   // V transposed: Vt[d][key]
  __shared__ __align__(16) short Pl[4][16][LDSTR];

  const int bh   = blockIdx.x;       // b*16 + h
  const int qt   = blockIdx.y;
  const int b    = bh >> 4;
  const int tid  = threadIdx.x;
  const int wid  = tid >> 6;
  const int lane = tid & 63;
  const int lr   = lane & 15;        // C-layout col / A-layout row
  const int lg   = lane >> 4;        // lane group 0..3

  const size_t base  = (size_t)bh * SEQ * DK;
  const int    qrow0 = qt * QB + wid * 16;   // this wave's first q row

  // ---- Q fragments in registers, pre-scaled by 1/sqrt(64) ----
  s16x8 qf[2];
  {
    const float* qp = Q + base + (size_t)(qrow0 + lr) * DK + lg * 8;
#pragma unroll
    for (int kk = 0; kk < 2; ++kk) {
      float4 a  = *(const float4*)(qp + kk * 32);
      float4 b4 = *(const float4*)(qp + kk * 32 + 4);
      float t8[8] = {a.x, a.y, a.z, a.w, b4.x, b4.y, b4.z, b4.w};
#pragma unroll
      for (int j = 0; j < 8; ++j) qf[kk][j] = f2bf(t8[j] * 0.125f);
    }
  }

  f32x4 oacc[4];
#pragma unroll
  for (int i = 0; i < 4; ++i) oacc[i] = (f32x4){0.f, 0.f, 0.f, 0.f};
  float mreg[4] = {-1e30f, -1e30f, -1e30f, -1e30f};
  float lreg[4] = {0.f, 0.f, 0.f, 0.f};

  const int*      Mb  = M  + (size_t)b * SEQ * SEQ;
  const unsigned* Mpb = Mp + (size_t)b * SEQ * (SEQ / 32);

  // staging mapping: thread t -> key = t/4, d-range = (t%4)*16 .. +16
  const int skey = tid >> 2;
  const int sd   = (tid & 3) * 16;
  const float* Kg0 = K + base + sd;
  const float* Vg0 = V + base + sd;

  for (int kb = 0; kb < SEQ; kb += KVB) {
    __syncthreads();  // previous iteration's LDS reads done

    // ---- mask prefetch ----
    int mk[4][4];
    if (PACKED) {
      // row q = qrow0+lg*4+r, bits kb..kb+63 in two u32 words
#pragma unroll
      for (int r = 0; r < 4; ++r) {
        uint2 mw = *(const uint2*)&Mpb[(size_t)(qrow0 + lg * 4 + r) * (SEQ / 32) + (kb >> 5)];
#pragma unroll
        for (int nb = 0; nb < 4; ++nb) {
          unsigned w = (nb < 2) ? mw.x : mw.y;
          mk[nb][r] = (w >> ((nb & 1) * 16 + lr)) & 1u;
        }
      }
    } else {
#pragma unroll
      for (int nb = 0; nb < 4; ++nb)
#pragma unroll
        for (int r = 0; r < 4; ++r)
          mk[nb][r] = Mb[(size_t)(qrow0 + lg * 4 + r) * SEQ + (kb + nb * 16 + lr)];
    }

    // ---- stage K (row-major) + V (transposed): global fp32 -> bf16 LDS ----
    {
      const float* kg = Kg0 + (size_t)(kb + skey) * DK;
      const float* vg = Vg0 + (size_t)(kb + skey) * DK;
#pragma unroll
      for (int i = 0; i < 4; ++i) {
        float4 kv = *(const float4*)(kg + 4 * i);
        float4 vv = *(const float4*)(vg + 4 * i);
        s16x4 ks = { f2bf(kv.x), f2bf(kv.y), f2bf(kv.z), f2bf(kv.w) };
        *(s16x4*)&Kl[skey][sd + 4 * i] = ks;
        Vt[sd + 4 * i + 0][skey] = f2bf(vv.x);
        Vt[sd + 4 * i + 1][skey] = f2bf(vv.y);
        Vt[sd + 4 * i + 2][skey] = f2bf(vv.z);
        Vt[sd + 4 * i + 3][skey] = f2bf(vv.w);
      }
    }
    __syncthreads();

    // ---- scores: S = (Q/8) · K^T  (16 q-rows x 64 keys per wave) ----
    f32x4 sacc[4];
#pragma unroll
    for (int nb = 0; nb < 4; ++nb) {
      sacc[nb] = (f32x4){0.f, 0.f, 0.f, 0.f};
#pragma unroll
      for (int kk = 0; kk < 2; ++kk) {
        s16x8 kf = *(const s16x8*)&Kl[nb * 16 + lr][kk * 32 + lg * 8];
        sacc[nb] = __builtin_amdgcn_mfma_f32_16x16x32_bf16(qf[kk], kf, sacc[nb], 0, 0, 0);
      }
    }

    // ---- mask + row max ----
    float pm[4] = {-1e30f, -1e30f, -1e30f, -1e30f};
#pragma unroll
    for (int nb = 0; nb < 4; ++nb)
#pragma unroll
      for (int r = 0; r < 4; ++r) {
        float s = mk[nb][r] ? -1e9f : sacc[nb][r];
        sacc[nb][r] = s;
        pm[r] = fmaxf(pm[r], s);
      }
#pragma unroll
    for (int r = 0; r < 4; ++r) {
#pragma unroll
      for (int off = 1; off < 16; off <<= 1)
        pm[r] = fmaxf(pm[r], __shfl_xor(pm[r], off));
    }

    // ---- online softmax update ----
    float rs[4];
#pragma unroll
    for (int r = 0; r < 4; ++r) {
      float mn = fmaxf(mreg[r], pm[r]);
      float al = __expf(mreg[r] - mn);   // mreg init -1e30 -> al = 0 first tile, no NaN
      mreg[r] = mn;
      lreg[r] *= al;
#pragma unroll
      for (int db = 0; db < 4; ++db) oacc[db][r] *= al;
      rs[r] = 0.f;
    }

    // ---- P = exp(S - m) -> bf16 LDS (per-wave tile, C-layout write) ----
#pragma unroll
    for (int nb = 0; nb < 4; ++nb)
#pragma unroll
      for (int r = 0; r < 4; ++r) {
        float p = __expf(sacc[nb][r] - mreg[r]);
        rs[r] += p;
        Pl[wid][lg * 4 + r][nb * 16 + lr] = f2bf(p);
      }
#pragma unroll
    for (int r = 0; r < 4; ++r) {
#pragma unroll
      for (int off = 1; off < 16; off <<= 1)
        rs[r] += __shfl_xor(rs[r], off);
      lreg[r] += rs[r];
    }

    // same-wave cross-lane RAW through LDS: drain writes before A-frag reads
    asm volatile("s_waitcnt lgkmcnt(0)" ::: "memory");

    // ---- O += P · V ----
#pragma unroll
    for (int kk = 0; kk < 2; ++kk) {
      s16x8 pf = *(const s16x8*)&Pl[wid][lr][kk * 32 + lg * 8];
#pragma unroll
      for (int db = 0; db < 4; ++db) {
        s16x8 vf = *(const s16x8*)&Vt[db * 16 + lr][kk * 32 + lg * 8];  // vector row read
        oacc[db] = __builtin_amdgcn_mfma_f32_16x16x32_bf16(pf, vf, oacc[db], 0, 0, 0);
      }
    }
  }

  // ---- epilogue: O / l, fp32 store ----
#pragma unroll
  for (int r = 0; r < 4; ++r) {
    float inv = 1.0f / lreg[r];
    float* op = O + base + (size_t)(qrow0 + lg * 4 + r) * DK + lr;
#pragma unroll
    for (int db = 0; db < 4; ++db)
      op[db * 16] = oacc[db][r] * inv;
  }
}

extern "C" void kernel_launch(void* const* d_in, const int* in_sizes, int n_in,
                              void* d_out, int out_size, void* d_ws, size_t ws_size,
                              hipStream_t stream) {
  const float* Q = (const float*)d_in[0];
  const float* K = (const float*)d_in[1];
  const float* V = (const float*)d_in[2];
  const int*   M = (const int*)d_in[3];
  float*       O = (float*)d_out;
  dim3 grid(NBH, SEQ / QB);   // x = b*H+h (heads adjacent -> mask L2 reuse), y = q-tile

  if (ws_size >= (size_t)MASK_WORDS * 4) {
    unsigned* Mp = (unsigned*)d_ws;
    mask_pack_kernel<<<MASK_WORDS / 256, 256, 0, stream>>>(M, Mp);
    sda_attn_kernel<true><<<grid, 256, 0, stream>>>(Q, K, V, M, Mp, O);
  } else {
    sda_attn_kernel<false><<<grid, 256, 0, stream>>>(Q, K, V, M, nullptr, O);
  }
}

// Round 3
// 247.858 us; speedup vs baseline: 1.3729x; 1.1872x over previous
//
#include <hip/hip_runtime.h>
#include <hip/hip_bf16.h>

// ScaledDotAttention: B=4, H=16, S=2048, D=64, fp32 in/out, int mask (nonzero = masked out).
// R3: swapped QK^T (S^T in registers, in-register softmax, no P LDS round-trip),
//     XOR-swizzled LDS (conflict-floor b128 reads), exp2-domain softmax,
//     bpermute P-exchange for PV, T14 register prefetch of next K/V tile.

#define SEQ   2048
#define DK    64
#define NB_   4
#define NBH   64
#define KVB   64
#define QB    64
#define MASK_WORDS (NB_ * SEQ * (SEQ / 32))   // 2 MB in d_ws

typedef float f32x4 __attribute__((ext_vector_type(4)));
typedef short s16x8 __attribute__((ext_vector_type(8)));

__device__ __forceinline__ unsigned f2bf(float f) {
  __hip_bfloat16 h = __float2bfloat16(f);   // RNE
  return (unsigned)*reinterpret_cast<unsigned short*>(&h);
}

#if __has_builtin(__builtin_amdgcn_exp2f)
#define EXP2F(x) __builtin_amdgcn_exp2f(x)
#else
#define EXP2F(x) __expf((x) * 0.6931471805599453f)
#endif

// (1/sqrt(64)) * log2(e): scores live in log2 domain -> exp2 for softmax
#define QSCALE 0.18033688011112042f

// swizzled LDS element offset for [row][64] bf16 tiles: XOR byte bits 4..6 with row&7
__device__ __forceinline__ int swz(int row, int col) {
  return row * 64 + (col ^ ((row & 7) << 3));
}

__global__ __launch_bounds__(256) void mask_pack_kernel(const int* __restrict__ M,
                                                        unsigned* __restrict__ P) {
  int w = blockIdx.x * 256 + threadIdx.x;
  const int4* src = (const int4*)M + (size_t)w * 8;
  unsigned bits = 0;
#pragma unroll
  for (int i = 0; i < 8; ++i) {
    int4 v = src[i];
    bits |= ((unsigned)(v.x != 0) << (4 * i)) | ((unsigned)(v.y != 0) << (4 * i + 1)) |
            ((unsigned)(v.z != 0) << (4 * i + 2)) | ((unsigned)(v.w != 0) << (4 * i + 3));
  }
  P[w] = bits;
}

template <bool PACKED>
__global__ __launch_bounds__(256, 4) void sda_attn_kernel(
    const float* __restrict__ Q, const float* __restrict__ K,
    const float* __restrict__ V, const int* __restrict__ M,
    const unsigned* __restrict__ Mp, float* __restrict__ O) {
  __shared__ __align__(16) short Kl[KVB * DK];   // [key][d], swizzled
  __shared__ __align__(16) short Vt[DK * KVB];   // [d][key], swizzled

  const int bh   = blockIdx.x;
  const int qt   = blockIdx.y;
  const int b    = bh >> 4;
  const int tid  = threadIdx.x;
  const int wid  = tid >> 6;
  const int lane = tid & 63;
  const int lr   = lane & 15;   // q index within wave tile
  const int lg   = lane >> 4;   // lane group 0..3

  const size_t base  = (size_t)bh * SEQ * DK;
  const int    q     = qt * QB + wid * 16 + lr;   // this lane's q row

  // ---- Q B-frag: lane holds Q[q][kk*32 + lg*8 + j], pre-scaled ----
  s16x8 qf[2];
  {
    const float* qp = Q + base + (size_t)q * DK + lg * 8;
#pragma unroll
    for (int kk = 0; kk < 2; ++kk) {
      float4 A  = *(const float4*)(qp + kk * 32);
      float4 Bv = *(const float4*)(qp + kk * 32 + 4);
      unsigned u0 = f2bf(A.x * QSCALE)  | (f2bf(A.y * QSCALE) << 16);
      unsigned u1 = f2bf(A.z * QSCALE)  | (f2bf(A.w * QSCALE) << 16);
      unsigned u2 = f2bf(Bv.x * QSCALE) | (f2bf(Bv.y * QSCALE) << 16);
      unsigned u3 = f2bf(Bv.z * QSCALE) | (f2bf(Bv.w * QSCALE) << 16);
      qf[kk] = __builtin_bit_cast(s16x8, make_uint4(u0, u1, u2, u3));
    }
  }

  f32x4 oacc[4];
#pragma unroll
  for (int i = 0; i < 4; ++i) oacc[i] = (f32x4){0.f, 0.f, 0.f, 0.f};
  float mreg = -1e30f, lreg = 0.f;

  // staging maps
  const int krow = tid >> 2, kcol = (tid & 3) * 16;          // K: row-major
  const int kp   = tid & 31, d8   = (tid >> 5) * 8;          // V: key-pair transpose
  const float* Kg  = K + base + (size_t)krow * DK + kcol;
  const float* Vg0 = V + base + (size_t)(2 * kp) * DK + d8;
  const float* Vg1 = Vg0 + DK;

  float4 kpre[4], vpre[4];
#define LOADT(kb_)                                                       \
  {                                                                      \
    const float* kg = Kg + (size_t)(kb_)*DK;                             \
    _Pragma("unroll") for (int i = 0; i < 4; ++i)                        \
        kpre[i] = *(const float4*)(kg + 4 * i);                          \
    const float* va = Vg0 + (size_t)(kb_)*DK;                            \
    const float* vb = Vg1 + (size_t)(kb_)*DK;                            \
    vpre[0] = *(const float4*)va; vpre[1] = *(const float4*)(va + 4);    \
    vpre[2] = *(const float4*)vb; vpre[3] = *(const float4*)(vb + 4);    \
  }
  LOADT(0);

  const unsigned* Mrow   = PACKED ? Mp + (size_t)b * SEQ * (SEQ / 32) + (size_t)q * (SEQ / 32) : nullptr;
  const int*      Mrow32 = PACKED ? nullptr : M + (size_t)b * SEQ * SEQ + (size_t)q * SEQ;

  for (int kb = 0; kb < SEQ; kb += KVB) {
    __syncthreads();   // previous tile's LDS reads done

    // ---- stage K (swizzled row-major) from prefetch regs ----
    {
      unsigned kw[8];
#pragma unroll
      for (int i = 0; i < 4; ++i) {
        kw[2 * i]     = f2bf(kpre[i].x) | (f2bf(kpre[i].y) << 16);
        kw[2 * i + 1] = f2bf(kpre[i].z) | (f2bf(kpre[i].w) << 16);
      }
      *(uint4*)&Kl[swz(krow, kcol)]     = make_uint4(kw[0], kw[1], kw[2], kw[3]);
      *(uint4*)&Kl[swz(krow, kcol + 8)] = make_uint4(kw[4], kw[5], kw[6], kw[7]);
    }
    // ---- stage V transposed (swizzled): u32 = {key 2kp, key 2kp+1} at row d ----
    {
      const float* va = (const float*)&vpre[0];   // V[2kp][d8..d8+7]
      const float* vc = (const float*)&vpre[2];   // V[2kp+1][d8..d8+7]
#pragma unroll
      for (int j = 0; j < 8; ++j) {
        int d = d8 + j;
        unsigned u = f2bf(va[j]) | (f2bf(vc[j]) << 16);
        *(unsigned*)&Vt[d * 64 + ((2 * kp) ^ ((d & 7) << 3))] = u;
      }
    }
    __syncthreads();

    if (kb + KVB < SEQ) LOADT(kb + KVB);   // T14: next-tile VMEM in flight under compute

    // ---- mask words for this lane's q row ----
    unsigned a0 = 0, a1 = 0;
    int m16[4][4];
    if (PACKED) {
      uint2 mw = *(const uint2*)&Mrow[kb >> 5];
      a0 = mw.x >> (lg * 4);
      a1 = mw.y >> (lg * 4);
    } else {
#pragma unroll
      for (int nb = 0; nb < 4; ++nb)
#pragma unroll
        for (int r = 0; r < 4; ++r)
          m16[nb][r] = Mrow32[kb + nb * 16 + lg * 4 + r];
    }

    // ---- swapped QK^T: sc[nb] holds S^T[kv = nb*16 + lg*4 + r][q] ----
    f32x4 sc[4];
#pragma unroll
    for (int nb = 0; nb < 4; ++nb) {
      sc[nb] = (f32x4){0.f, 0.f, 0.f, 0.f};
#pragma unroll
      for (int kk = 0; kk < 2; ++kk) {
        s16x8 kf = *(const s16x8*)&Kl[swz(nb * 16 + lr, kk * 32 + lg * 8)];
        sc[nb] = __builtin_amdgcn_mfma_f32_16x16x32_bf16(kf, qf[kk], sc[nb], 0, 0, 0);
      }
    }

    // ---- row max over raw scores (masked included: safe upper bound) ----
    float mx = fmaxf(fmaxf(sc[0][0], sc[0][1]), fmaxf(sc[0][2], sc[0][3]));
#pragma unroll
    for (int nb = 1; nb < 4; ++nb)
      mx = fmaxf(mx, fmaxf(fmaxf(sc[nb][0], sc[nb][1]), fmaxf(sc[nb][2], sc[nb][3])));
    mx = fmaxf(mx, __shfl_xor(mx, 16));
    mx = fmaxf(mx, __shfl_xor(mx, 32));

    float mn = fmaxf(mreg, mx);
    float al = EXP2F(mreg - mn);
    mreg = mn;
    lreg *= al;
#pragma unroll
    for (int db = 0; db < 4; ++db) oacc[db] *= al;

    // ---- P = exp2(S - m), masked -> 0; pack bf16 pairs ----
    float rs = 0.f;
    unsigned pk[4][2];
#pragma unroll
    for (int nb = 0; nb < 4; ++nb) {
      unsigned w  = (nb < 2) ? a0 : a1;
      int      sh = (nb & 1) * 16;
      float e[4];
#pragma unroll
      for (int r = 0; r < 4; ++r) {
        float ev = EXP2F(sc[nb][r] - mn);
        bool msk = PACKED ? (((w >> (sh + r)) & 1u) != 0u) : (m16[nb][r] != 0);
        ev = msk ? 0.f : ev;
        rs += ev;
        e[r] = ev;
      }
      pk[nb][0] = f2bf(e[0]) | (f2bf(e[1]) << 16);
      pk[nb][1] = f2bf(e[2]) | (f2bf(e[3]) << 16);
    }
    rs += __shfl_xor(rs, 16);
    rs += __shfl_xor(rs, 32);
    lreg += rs;

    // ---- exchange P^T -> PV B-frag (lane needs P[q][kv = 32kk + 8lg + j]) ----
    // source word pk[2kk + (lane>>5)][w&1] from lane lr + 32*(lg&1) + 16*(w>>1)
    const int src0 = lr + 32 * (lg & 1);
    const int src1 = src0 + 16;
#pragma unroll
    for (int kk = 0; kk < 2; ++kk) {
      unsigned lo, hi, w0, w1, w2, w3;
      lo = __shfl(pk[2 * kk][0], src0); hi = __shfl(pk[2 * kk + 1][0], src0);
      w0 = (lane & 32) ? hi : lo;
      lo = __shfl(pk[2 * kk][1], src0); hi = __shfl(pk[2 * kk + 1][1], src0);
      w1 = (lane & 32) ? hi : lo;
      lo = __shfl(pk[2 * kk][0], src1); hi = __shfl(pk[2 * kk + 1][0], src1);
      w2 = (lane & 32) ? hi : lo;
      lo = __shfl(pk[2 * kk][1], src1); hi = __shfl(pk[2 * kk + 1][1], src1);
      w3 = (lane & 32) ? hi : lo;
      s16x8 ptf = __builtin_bit_cast(s16x8, make_uint4(w0, w1, w2, w3));

      // ---- PV: O^T[d][q] += V^T[d][kv] * P^T[kv][q] ----
#pragma unroll
      for (int db = 0; db < 4; ++db) {
        s16x8 vf = *(const s16x8*)&Vt[swz(db * 16 + lr, kk * 32 + lg * 8)];
        oacc[db] = __builtin_amdgcn_mfma_f32_16x16x32_bf16(vf, ptf, oacc[db], 0, 0, 0);
      }
    }
  }

  // ---- epilogue: lane holds O^T[d = db*16 + lg*4 + i][q]; store O[q][d] ----
  float inv = (lreg > 0.f) ? 1.0f / lreg : 0.f;
  float* op = O + base + (size_t)q * DK + lg * 4;
#pragma unroll
  for (int db = 0; db < 4; ++db) {
    float4 o;
    o.x = oacc[db][0] * inv;
    o.y = oacc[db][1] * inv;
    o.z = oacc[db][2] * inv;
    o.w = oacc[db][3] * inv;
    *(float4*)(op + db * 16) = o;
  }
}

extern "C" void kernel_launch(void* const* d_in, const int* in_sizes, int n_in,
                              void* d_out, int out_size, void* d_ws, size_t ws_size,
                              hipStream_t stream) {
  const float* Q = (const float*)d_in[0];
  const float* K = (const float*)d_in[1];
  const float* V = (const float*)d_in[2];
  const int*   M = (const int*)d_in[3];
  float*       O = (float*)d_out;
  dim3 grid(NBH, SEQ / QB);

  if (ws_size >= (size_t)MASK_WORDS * 4) {
    unsigned* Mp = (unsigned*)d_ws;
    mask_pack_kernel<<<MASK_WORDS / 256, 256, 0, stream>>>(M, Mp);
    sda_attn_kernel<true><<<grid, 256, 0, stream>>>(Q, K, V, M, Mp, O);
  } else {
    sda_attn_kernel<false><<<grid, 256, 0, stream>>>(Q, K, V, M, nullptr, O);
  }
}